// Round 3
// baseline (88.275 us; speedup 1.0000x reference)
//
#include <hip/hip_runtime.h>

#define N_BATCH 128
#define W_RAW   128
#define NSEG    (W_RAW - 1)             // 127 raw segments
#define W_UP    1024
#define TPB     256
#define QCHUNK  4                       // query chunks per (n,dir); 256 queries/block
#define QPB     256
#define NBLK    (N_BATCH * 2 * QCHUNK)  // 1024 blocks

// ws layout (floats):
//   partS[1024] | partP[1024] | partD[1024] | bidx[256*8] (int) |
//   t_up float2[128][1024] | p_up float2[128][1024] | m_up float[128][1024] |
//   segA float4[2][128][127] | segB float2[2][128][127]
#define WS_S  0
#define WS_P  1024
#define WS_D  2048
#define WS_I  3072                       // 2048 ints reserved
#define WS_T  8192                       // t_up, 262144 floats
#define WS_PP (WS_T + 2 * 128 * 1024)    // p_up, 262144 floats
#define WS_M  (WS_PP + 2 * 128 * 1024)   // m_up, 131072 floats
#define WS_GA (WS_M + 128 * 1024)        // segA, 2*128*127*4 floats
#define WS_GB (WS_GA + 2 * 128 * NSEG * 4) // segB, 2*128*127*2 floats

__device__ __forceinline__ void interp_setup(int i, int& i0, int& i1, float& w, float& w0) {
    const double step = 127.0 / 1023.0;       // align_corners=True linspace step (f64, np-like)
    double pos = (double)i * step;
    i0 = (int)pos;
    if (i0 > W_RAW - 1) i0 = W_RAW - 1;
    i1 = min(i0 + 1, W_RAW - 1);
    w  = (float)(pos - (double)i0);
    w0 = __fsub_rn(1.0f, w);
}

// one-shot precompute: upsampled curves (bit-exact interp), mask, segment tables.
// Removes ALL f64 interp + scattered raw loads from the hot chamfer kernel.
__global__ __launch_bounds__(TPB) void prep_kernel(
    const float* __restrict__ tp,
    const float* __restrict__ pr,
    const float* __restrict__ vm,
    float* __restrict__ ws)
{
    const int b   = blockIdx.x;
    const int tid = threadIdx.x;

    if (b < 256) {
        const int which = b >> 7;            // 0 = t curve, 1 = p curve
        const int n     = b & 127;
        const float* src   = (which == 0) ? tp : pr;
        const float* x_raw = src + (size_t)(n * 2 + 0) * W_RAW;
        const float* y_raw = src + (size_t)(n * 2 + 1) * W_RAW;
        float2* dst = (float2*)(ws + (which == 0 ? WS_T : WS_PP)) + (size_t)n * W_UP;

        #pragma unroll
        for (int k = 0; k < W_UP / TPB; ++k) {
            const int i = tid + k * TPB;
            int i0, i1; float w, w0;
            interp_setup(i, i0, i1, w, w0);
            const float cx = __fadd_rn(__fmul_rn(x_raw[i0], w0), __fmul_rn(x_raw[i1], w));
            const float cy = __fadd_rn(__fmul_rn(y_raw[i0], w0), __fmul_rn(y_raw[i1], w));
            dst[i] = make_float2(cx, cy);
        }

        // per-segment projection precompute (verified bit-exact vs numpy --
        // do NOT refactor the float op order)
        if (tid < NSEG) {
            const int s = tid;
            const float ax = x_raw[s],     ay = y_raw[s];
            const float bx = x_raw[s + 1], by = y_raw[s + 1];
            const float abx = bx - ax, aby = by - ay;
            const float len2 = abx * abx + aby * aby;
            const float inv  = (len2 > 0.0f) ? (1.0f / len2) : 0.0f;
            const float Kx = abx * inv, Ky = aby * inv;
            const float bb = -(ax * abx + ay * aby) * inv;
            const float s8h = (float)s * (1023.0f / 127.0f) + 0.5f;  // +0.5: round via trunc
            ((float4*)(ws + WS_GA))[(size_t)(which * 128 + n) * NSEG + s] =
                make_float4(Kx, Ky, bb, s8h);
            ((float2*)(ws + WS_GB))[(size_t)(which * 128 + n) * NSEG + s] =
                make_float2((float)((s * 1023 + 126) / 127),
                            (float)(((s + 1) * 1023) / 127));
        }
    } else {
        const int n = b - 256;               // 128 mask rows
        const float* m_raw = vm + (size_t)n * W_RAW;
        float* dst = ws + WS_M + (size_t)n * W_UP;
        #pragma unroll
        for (int k = 0; k < W_UP / TPB; ++k) {
            const int i = tid + k * TPB;
            int i0, i1; float w, w0;
            interp_setup(i, i0, i1, w, w0);
            // store RAW interp value; threshold applied at use (identical ops to before)
            dst[i] = __fadd_rn(__fmul_rn(m_raw[i0], w0), __fmul_rn(m_raw[i1], w));
        }
    }
}

__global__ __launch_bounds__(TPB) void chamfer_kernel(
    float* __restrict__ ws)
{
    __shared__ float2 s_c[W_UP];            // candidate curve (8 KB)
    __shared__ int    s_pi[QPB];            // per-query argmin index (1 KB)
    __shared__ float  s_red[4 * 3];

    const int bid    = blockIdx.x;
    const int qchunk = bid & (QCHUNK - 1);
    const int dir    = (bid >> 2) & 1;      // 0: query=t cand=p ; 1: query=p cand=t
    const int n      = bid >> 3;
    const int tid    = threadIdx.x;
    const int nd     = n * 2 + dir;

    const int cw = (dir == 0) ? 1 : 0;      // candidate curve id (0=t,1=p)
    const float2* ccur = (const float2*)(ws + (cw ? WS_PP : WS_T)) + (size_t)n * W_UP;
    const float2* qcur = (const float2*)(ws + (cw ? WS_T : WS_PP)) + (size_t)n * W_UP;
    const float4* gA   = (const float4*)(ws + WS_GA) + (size_t)(cw * 128 + n) * NSEG;
    const float2* gB   = (const float2*)(ws + WS_GB) + (size_t)(cw * 128 + n) * NSEG;

    // stage candidate curve: coalesced float4 loads, 2 per thread
    {
        const float4* c4  = (const float4*)ccur;
        float4*       s4  = (float4*)s_c;
        s4[tid]       = c4[tid];
        s4[tid + TPB] = c4[tid + TPB];
    }

    const int qi = qchunk * QPB + tid;      // one query per thread (same lane<->query
                                            // mapping as the verified kernel)
    const float2 q  = qcur[qi];
    const float  mv = ws[WS_M + (size_t)n * W_UP + qi];
    const float  mq = (mv < 0.5f) ? 0.0f : mv;   // jnp.where(m < 0.5, 0, m)
    __syncthreads();

    // scan all 127 segments, ascending s + strict '<' == numpy first-occurrence
    // (segment candidate ranges are disjoint & ascending). Segment tables are
    // read with a wave-uniform address -> scalar/global path, LDS pipe holds
    // only the per-lane s_c gather (<=9 distinct addrs over 18 banks: conflict-free).
    float bd = 3.4e38f;
    int   bi = 0;
    #pragma unroll 4
    for (int s = 0; s < NSEG; ++s) {
        const float4 SA = gA[s];
        const float2 SB = gB[s];
        const float t  = __builtin_fmaf(q.y, SA.y, __builtin_fmaf(q.x, SA.x, SA.z));
        float ic = __builtin_fmaf(t, 1023.0f / 127.0f, SA.w);
        ic = fminf(fmaxf(ic, SB.x), SB.y);
        const int i0 = (int)ic;             // trunc of (x+0.5) == round, ic >= 0
        const float2 c0 = s_c[i0];
        // exact f32 distance form (matches numpy bit-for-bit)
        const float dx0 = __fsub_rn(q.x, c0.x);
        const float dy0 = __fsub_rn(q.y, c0.y);
        const float d0  = __fadd_rn(__fmul_rn(dx0, dx0), __fmul_rn(dy0, dy0));
        const bool lt = d0 < bd;
        bd = lt ? d0 : bd;
        bi = lt ? i0 : bi;
    }

    s_pi[tid] = bi;

    // compact boundary-index export for finalize's chunk-boundary penalty patch
    if (tid == 0)       ((int*)(ws + WS_I))[nd * 8 + qchunk * 2 + 0] = bi;
    if (tid == QPB - 1) ((int*)(ws + WS_I))[nd * 8 + qchunk * 2 + 1] = bi;

    float S = bd * mq;
    float D = 0.0f;
    if (dir == 0) {   // direct (aligned) error, once per batch row
        const float2 c = s_c[qi];
        const float dx = q.x - c.x;
        const float dy = q.y - c.y;
        D = (dx * dx + dy * dy) * mq;
    }
    __syncthreads();

    // order penalty, block-internal pairs; chunk-boundary pairs patched in finalize
    float P = 0.0f;
    if (tid < QPB - 1) {
        const float df = (float)(s_pi[tid] - s_pi[tid + 1]);
        const float r  = fmaxf(df, 0.0f);
        P = r * r * mq;
    }

    // block reduction (identical structure/order to the verified kernel)
    #pragma unroll
    for (int off = 32; off > 0; off >>= 1) {
        S += __shfl_down(S, off, 64);
        P += __shfl_down(P, off, 64);
        D += __shfl_down(D, off, 64);
    }
    const int wave = tid >> 6, lane = tid & 63;
    if (lane == 0) {
        s_red[wave * 3 + 0] = S;
        s_red[wave * 3 + 1] = P;
        s_red[wave * 3 + 2] = D;
    }
    __syncthreads();
    if (tid == 0) {
        float St = 0.f, Pt = 0.f, Dt = 0.f;
        #pragma unroll
        for (int w2 = 0; w2 < TPB / 64; ++w2) {
            St += s_red[w2 * 3 + 0];
            Pt += s_red[w2 * 3 + 1];
            Dt += s_red[w2 * 3 + 2];
        }
        ws[WS_S + bid] = St;
        ws[WS_P + bid] = Pt;
        ws[WS_D + bid] = Dt;   // 0 for dir==1 blocks
    }
}

__global__ __launch_bounds__(TPB) void finalize_kernel(
    const float* __restrict__ ws,
    float* __restrict__ out)
{
    __shared__ float s_red[4 * 3];
    const int tid = threadIdx.x;

    float S = 0.f, P = 0.f, D = 0.f;
    #pragma unroll
    for (int k = 0; k < NBLK / TPB; ++k) {
        const int b = tid + k * TPB;
        S += ws[WS_S + b];
        P += ws[WS_P + b];
        D += ws[WS_D + b];
    }

    // chunk-boundary penalty pairs: 3 per (n,dir) at i = b*256-1, b in {1,2,3}
    const int* wsI = (const int*)(ws + WS_I);
    for (int e = tid; e < N_BATCH * 2 * (QCHUNK - 1); e += TPB) {  // 768
        const int ndb = e / (QCHUNK - 1);
        const int b   = e % (QCHUNK - 1) + 1;
        const int i   = b * QPB - 1;
        const int nn  = ndb >> 1;
        const int idx_last  = wsI[ndb * 8 + (b - 1) * 2 + 1];  // widx[i]
        const int idx_first = wsI[ndb * 8 + b * 2 + 0];        // widx[i+1]
        const float df = (float)(idx_last - idx_first);
        const float r  = fmaxf(df, 0.0f);
        const float mv = ws[WS_M + (size_t)nn * W_UP + i];     // identical interp value
        const float mq = (mv < 0.5f) ? 0.0f : mv;
        P += r * r * mq;
    }

    #pragma unroll
    for (int off = 32; off > 0; off >>= 1) {
        S += __shfl_down(S, off, 64);
        P += __shfl_down(P, off, 64);
        D += __shfl_down(D, off, 64);
    }
    const int wave = tid >> 6, lane = tid & 63;
    if (lane == 0) {
        s_red[wave * 3 + 0] = S;
        s_red[wave * 3 + 1] = P;
        s_red[wave * 3 + 2] = D;
    }
    __syncthreads();
    if (tid == 0) {
        float St = 0.f, Pt = 0.f, Dt = 0.f;
        #pragma unroll
        for (int w2 = 0; w2 < TPB / 64; ++w2) {
            St += s_red[w2 * 3 + 0];
            Pt += s_red[w2 * 3 + 1];
            Dt += s_red[w2 * 3 + 2];
        }
        const float nw  = (float)(N_BATCH * W_UP);         // 131072
        const float nw1 = (float)(N_BATCH * (W_UP - 1));   // 130944
        const float matched = St / (2.0f * nw) + 0.1f * Pt / (2.0f * nw1);
        const float direct  = Dt / nw;
        out[0] = fminf(matched, direct);
    }
}

extern "C" void kernel_launch(void* const* d_in, const int* in_sizes, int n_in,
                              void* d_out, int out_size, void* d_ws, size_t ws_size,
                              hipStream_t stream) {
    const float* tp = (const float*)d_in[0];
    const float* pr = (const float*)d_in[1];
    const float* vm = (const float*)d_in[2];
    float* out = (float*)d_out;
    float* ws  = (float*)d_ws;

    prep_kernel<<<384, TPB, 0, stream>>>(tp, pr, vm, ws);
    chamfer_kernel<<<NBLK, TPB, 0, stream>>>(ws);
    finalize_kernel<<<1, TPB, 0, stream>>>(ws, out);
}

// Round 4
// 74.536 us; speedup vs baseline: 1.1843x; 1.1843x over previous
//
#include <hip/hip_runtime.h>

#define N_BATCH 128
#define W_RAW   128
#define NSEG    (W_RAW - 1)             // 127 raw segments
#define W_UP    1024
#define TPB     256
#define QCHUNK  4                       // query chunks per (n,dir); 256 queries/block
#define QPB     256
#define SCHUNK  4                       // segment chunks within a block (wave-uniform)
#define SPC     32                      // segments per chunk (last chunk has 31)
#define NBLK    (N_BATCH * 2 * QCHUNK)  // 1024 blocks

// ws layout (floats): partS[1024] | partP[1024] | partD[1024] | widx[2*128*1024] (int)
#define WS_S 0
#define WS_P 1024
#define WS_D 2048
#define WS_I 3072

__device__ __forceinline__ void interp_setup(int i, int& i0, int& i1, float& w, float& w0) {
    const double step = 127.0 / 1023.0;       // align_corners=True linspace step (f64, np-like)
    double pos = (double)i * step;
    i0 = (int)pos;
    if (i0 > W_RAW - 1) i0 = W_RAW - 1;
    i1 = min(i0 + 1, W_RAW - 1);
    w  = (float)(pos - (double)i0);
    w0 = __fsub_rn(1.0f, w);
}

__global__ __launch_bounds__(TPB) void chamfer_kernel(
    const float* __restrict__ tp,   // target_points   (N, 2, 128)
    const float* __restrict__ pr,   // predictions     (N, 2, 128)
    const float* __restrict__ vm,   // visibility_mask (N, 128)
    float* __restrict__ ws)
{
    __shared__ float2 s_c[W_UP];            // interpolated candidate curve (8 KB)
    __shared__ float4 s_segA[NSEG];         // Kx, Ky, b, s*1023/127 + 0.5 (~2 KB)
    __shared__ float2 s_segB[NSEG];         // lo_f, hi_f (integer-valued) (~1 KB)
    __shared__ float  s_pd[SCHUNK][QPB];    // per-chunk best distance     (4 KB)
    __shared__ int    s_pi[SCHUNK][QPB];    // per-chunk best index; row 0 reused as merged (4 KB)
    __shared__ float  s_red[4 * 3];

    const int bid    = blockIdx.x;
    const int qchunk = bid & (QCHUNK - 1);
    const int dir    = (bid >> 2) & 1;      // 0: query=t cand=p ; 1: query=p cand=t
    const int n      = bid >> 3;
    const int tid    = threadIdx.x;
    const int nd     = n * 2 + dir;

    const float* q_base = (dir == 0) ? tp : pr;
    const float* c_base = (dir == 0) ? pr : tp;
    const float* qx_raw = q_base + (size_t)(n * 2 + 0) * W_RAW;
    const float* qy_raw = q_base + (size_t)(n * 2 + 1) * W_RAW;
    const float* cx_raw = c_base + (size_t)(n * 2 + 0) * W_RAW;
    const float* cy_raw = c_base + (size_t)(n * 2 + 1) * W_RAW;
    const float* m_raw  = vm + (size_t)n * W_RAW;

    // stage full candidate curve (4 points/thread), bit-exact interp
    #pragma unroll
    for (int k = 0; k < W_UP / TPB; ++k) {
        const int i = tid + k * TPB;
        int i0, i1; float w, w0;
        interp_setup(i, i0, i1, w, w0);
        const float cx = __fadd_rn(__fmul_rn(cx_raw[i0], w0), __fmul_rn(cx_raw[i1], w));
        const float cy = __fadd_rn(__fmul_rn(cy_raw[i0], w0), __fmul_rn(cy_raw[i1], w));
        s_c[i] = make_float2(cx, cy);
    }

    // per-segment projection precompute: t(q) = dot(q,K)+b is the line
    // parameter; round(s8 + t*1023/127) clamped to [lo,hi] is the in-range
    // integer argmin of the exact distance parabola over candidate indices.
    // (t-clamp folded into the float ic-clamp: equivalent by case analysis,
    // since s8h < lo+0.5 and s8h+8.055 >= hi+0.5, bounds are exact integers.)
    if (tid < NSEG) {
        const int s = tid;
        const float ax = cx_raw[s],     ay = cy_raw[s];
        const float bx = cx_raw[s + 1], by = cy_raw[s + 1];
        const float abx = bx - ax, aby = by - ay;
        const float len2 = abx * abx + aby * aby;
        const float inv  = (len2 > 0.0f) ? (1.0f / len2) : 0.0f;
        const float Kx = abx * inv, Ky = aby * inv;
        const float bb = -(ax * abx + ay * aby) * inv;
        const float s8h = (float)s * (1023.0f / 127.0f) + 0.5f;  // +0.5: round via trunc
        s_segA[s] = make_float4(Kx, Ky, bb, s8h);
        s_segB[s] = make_float2((float)((s * 1023 + 126) / 127),
                                (float)(((s + 1) * 1023) / 127));
    }

    // scan-phase mapping: 64 query-groups x 4 segment-chunks (wave-uniform chunk)
    const int jc = tid >> 6;
    const int g  = tid & 63;

    float qx[4], qy[4];
    #pragma unroll
    for (int k = 0; k < 4; ++k) {
        const int qi = qchunk * QPB + g * 4 + k;
        int i0, i1; float w, w0;
        interp_setup(qi, i0, i1, w, w0);
        qx[k] = __fadd_rn(__fmul_rn(qx_raw[i0], w0), __fmul_rn(qx_raw[i1], w));
        qy[k] = __fadd_rn(__fmul_rn(qy_raw[i0], w0), __fmul_rn(qy_raw[i1], w));
    }
    __syncthreads();

    float bestd[4];
    int   bidx[4];
    #pragma unroll
    for (int k = 0; k < 4; ++k) { bestd[k] = 3.4e38f; bidx[k] = 0; }

    const int sbase = jc * SPC;
    const int send  = min(sbase + SPC, NSEG);
    #pragma unroll 4
    for (int s = sbase; s < send; ++s) {
        const float4 SA = s_segA[s];   // wave-uniform -> broadcast
        const float2 SB = s_segB[s];
        #pragma unroll
        for (int k = 0; k < 4; ++k) {
            const float t  = __builtin_fmaf(qy[k], SA.y, __builtin_fmaf(qx[k], SA.x, SA.z));
            float ic = __builtin_fmaf(t, 1023.0f / 127.0f, SA.w);
            ic = fminf(fmaxf(ic, SB.x), SB.y);
            const int i0 = (int)ic;            // trunc of (x+0.5) == round, ic >= 0
            const float2 c0 = s_c[i0];
            // exact f32 distance form (matches numpy bit-for-bit)
            const float dx0 = __fsub_rn(qx[k], c0.x);
            const float dy0 = __fsub_rn(qy[k], c0.y);
            const float d0  = __fadd_rn(__fmul_rn(dx0, dx0), __fmul_rn(dy0, dy0));
            // ascending index order + strict '<' == numpy first-occurrence
            const bool lt = d0 < bestd[k];
            bestd[k] = lt ? d0 : bestd[k];
            bidx[k]  = lt ? i0 : bidx[k];
        }
    }

    #pragma unroll
    for (int k = 0; k < 4; ++k) {
        const int q = g * 4 + k;
        s_pd[jc][q] = bestd[k];
        s_pi[jc][q] = bidx[k];
    }
    __syncthreads();

    // merge phase: one query per thread (q = tid); ascending chunk (= ascending
    // candidate index) + strict '<' keeps the earliest-index winner.
    // Column-local read-then-write lets us reuse s_pi[0] as the merged array.
    float bd = s_pd[0][tid];
    int   bi = s_pi[0][tid];
    #pragma unroll
    for (int c = 1; c < SCHUNK; ++c) {
        const float d2 = s_pd[c][tid];
        const bool lt = d2 < bd;
        bd = lt ? d2 : bd;
        bi = lt ? s_pi[c][tid] : bi;
    }
    s_pi[0][tid] = bi;

    const int qi = qchunk * QPB + tid;
    ((int*)(ws + WS_I))[(size_t)nd * W_UP + qi] = bi;   // for chunk-boundary patch

    // this query's interp + mask
    int i0m, i1m; float wm, w0m;
    interp_setup(qi, i0m, i1m, wm, w0m);
    const float qxm = __fadd_rn(__fmul_rn(qx_raw[i0m], w0m), __fmul_rn(qx_raw[i1m], wm));
    const float qym = __fadd_rn(__fmul_rn(qy_raw[i0m], w0m), __fmul_rn(qy_raw[i1m], wm));
    const float mv  = __fadd_rn(__fmul_rn(m_raw[i0m], w0m), __fmul_rn(m_raw[i1m], wm));
    const float mq  = (mv < 0.5f) ? 0.0f : mv;          // jnp.where(m < 0.5, 0, m)

    float S = bd * mq;
    float D = 0.0f;
    if (dir == 0) {   // direct (aligned) error, once per batch row
        const float2 c = s_c[qi];
        const float dx = qxm - c.x;
        const float dy = qym - c.y;
        D = (dx * dx + dy * dy) * mq;
    }
    __syncthreads();

    // order penalty, block-internal pairs; chunk-boundary pairs patched in finalize
    float P = 0.0f;
    if (tid < QPB - 1) {
        const float df = (float)(s_pi[0][tid] - s_pi[0][tid + 1]);
        const float r  = fmaxf(df, 0.0f);
        P = r * r * mq;
    }

    // block reduction
    #pragma unroll
    for (int off = 32; off > 0; off >>= 1) {
        S += __shfl_down(S, off, 64);
        P += __shfl_down(P, off, 64);
        D += __shfl_down(D, off, 64);
    }
    const int wave = tid >> 6, lane = tid & 63;
    if (lane == 0) {
        s_red[wave * 3 + 0] = S;
        s_red[wave * 3 + 1] = P;
        s_red[wave * 3 + 2] = D;
    }
    __syncthreads();
    if (tid == 0) {
        float St = 0.f, Pt = 0.f, Dt = 0.f;
        #pragma unroll
        for (int w2 = 0; w2 < TPB / 64; ++w2) {
            St += s_red[w2 * 3 + 0];
            Pt += s_red[w2 * 3 + 1];
            Dt += s_red[w2 * 3 + 2];
        }
        ws[WS_S + bid] = St;
        ws[WS_P + bid] = Pt;
        ws[WS_D + bid] = Dt;   // 0 for dir==1 blocks
    }
}

__global__ __launch_bounds__(TPB) void finalize_kernel(
    const float* __restrict__ vm,
    const float* __restrict__ ws,
    float* __restrict__ out)
{
    __shared__ float s_red[4 * 3];
    const int tid = threadIdx.x;

    float S = 0.f, P = 0.f, D = 0.f;
    #pragma unroll
    for (int k = 0; k < NBLK / TPB; ++k) {
        const int b = tid + k * TPB;
        S += ws[WS_S + b];
        P += ws[WS_P + b];
        D += ws[WS_D + b];
    }

    // chunk-boundary penalty pairs: 3 per (n,dir) at i = b*256-1, b in {1,2,3}
    if (tid < N_BATCH * 2 * (QCHUNK - 1)) {        // 768
        const int nd = tid / (QCHUNK - 1);         // n*2+dir
        const int b  = tid % (QCHUNK - 1) + 1;
        const int i  = b * QPB - 1;
        const int n  = nd >> 1;
        const int* widx = (const int*)(ws + WS_I) + (size_t)nd * W_UP;
        const float df = (float)(widx[i] - widx[i + 1]);
        const float r  = fmaxf(df, 0.0f);
        int i0, i1; float w, w0;
        interp_setup(i, i0, i1, w, w0);
        const float* m_raw = vm + (size_t)n * W_RAW;
        float mv = __fadd_rn(__fmul_rn(m_raw[i0], w0), __fmul_rn(m_raw[i1], w));
        const float mq = (mv < 0.5f) ? 0.0f : mv;
        P += r * r * mq;
    }

    #pragma unroll
    for (int off = 32; off > 0; off >>= 1) {
        S += __shfl_down(S, off, 64);
        P += __shfl_down(P, off, 64);
        D += __shfl_down(D, off, 64);
    }
    const int wave = tid >> 6, lane = tid & 63;
    if (lane == 0) {
        s_red[wave * 3 + 0] = S;
        s_red[wave * 3 + 1] = P;
        s_red[wave * 3 + 2] = D;
    }
    __syncthreads();
    if (tid == 0) {
        float St = 0.f, Pt = 0.f, Dt = 0.f;
        #pragma unroll
        for (int w2 = 0; w2 < TPB / 64; ++w2) {
            St += s_red[w2 * 3 + 0];
            Pt += s_red[w2 * 3 + 1];
            Dt += s_red[w2 * 3 + 2];
        }
        const float nw  = (float)(N_BATCH * W_UP);         // 131072
        const float nw1 = (float)(N_BATCH * (W_UP - 1));   // 130944
        const float matched = St / (2.0f * nw) + 0.1f * Pt / (2.0f * nw1);
        const float direct  = Dt / nw;
        out[0] = fminf(matched, direct);
    }
}

extern "C" void kernel_launch(void* const* d_in, const int* in_sizes, int n_in,
                              void* d_out, int out_size, void* d_ws, size_t ws_size,
                              hipStream_t stream) {
    const float* tp = (const float*)d_in[0];
    const float* pr = (const float*)d_in[1];
    const float* vm = (const float*)d_in[2];
    float* out = (float*)d_out;
    float* ws  = (float*)d_ws;

    chamfer_kernel<<<NBLK, TPB, 0, stream>>>(tp, pr, vm, ws);
    finalize_kernel<<<1, TPB, 0, stream>>>(vm, ws, out);
}